// Round 5
// baseline (496.773 us; speedup 1.0000x reference)
//
#include <hip/hip_runtime.h>
#include <hip/hip_bf16.h>

#define NIN    512
#define NEVAL  1536
#define NCOLS  2048
#define NOUT   256
#define OUT_BASE 1280
#define NBLK   48       // NEVAL / 32
#define RPW    8        // rows per workgroup

typedef __attribute__((ext_vector_type(8))) short short8;   // 8 bf16 (4 VGPRs)
typedef __attribute__((ext_vector_type(4))) float floatx4;  // MFMA C/D

// ---------- helpers ----------

__device__ __forceinline__ unsigned short f2bf(float f) {
    __hip_bfloat16 h = __float2bfloat16(f);
    return __builtin_bit_cast(unsigned short, h);
}
__device__ __forceinline__ unsigned pack2(float a, float b) {
    return (unsigned)f2bf(a) | ((unsigned)f2bf(b) << 16);
}
// sigmoid(clip(5z,-60,60)): clamp dropped — v_exp overflow gives exact 0/1.
__device__ __forceinline__ float sigmoid5(float z) {
    return __builtin_amdgcn_rcpf(1.0f + __expf(-5.0f * z));
}

// ---------- W fp32 -> bf16 (d_ws re-poisoned every launch, so rerun) ----------
// 8 floats -> one 16 B store per thread.

__global__ __launch_bounds__(256) void wconv(const float* __restrict__ W,
                                             ushort* __restrict__ Wb, int n8) {
    int i = blockIdx.x * blockDim.x + threadIdx.x;
    if (i < n8) {
        float4 v0 = ((const float4*)W)[2 * i];
        float4 v1 = ((const float4*)W)[2 * i + 1];
        uint4 pk;
        pk.x = pack2(v0.x, v0.y); pk.y = pack2(v0.z, v0.w);
        pk.z = pack2(v1.x, v1.y); pk.w = pack2(v1.z, v1.w);
        ((uint4*)Wb)[i] = pk;
    }
}

// ---------- main kernel ----------
// 512 WGs x 512 threads (8 waves) -> 2 WGs/CU: two INDEPENDENT dependency
// streams per CU so one WG's chain/latency bubbles are filled by the other
// (round 2==round 4 showed a single stream is stall-bound at ~60%).
// WG owns 8 batch rows; wave w owns row w. O[8][2048] bf16 in LDS, row r
// rotated by 8r elements. Per 32-node block k (cols [L0, L0+32), L0=512+32k):
//   tail:  one K=32 MFMA over [L0-32, L0), gated to its owning K-split slot
//   Zred:  8 waves' partials (2 node-halves x 4 K-splits) -> LDS -> gather
//   main:  MFMAs for block k+1 over [0, L0), K-split 4-way stride 128
//   chain: 32 sequential steps, readlane broadcast; wdg[jj]==0 for jj>=ii
// A-frag: lane m16 reads O row (m16&7) — rows 8..15 duplicate (broadcast,
// free); gather only consumes D rows 0..7.

__global__ __launch_bounds__(512, 4) void ffnet(const float* __restrict__ x,
                                                const float* __restrict__ W,
                                                const ushort* __restrict__ Wb,
                                                const float* __restrict__ bias,
                                                float* __restrict__ out) {
    __shared__ unsigned short O[RPW * 2048];  // 32 KB
    __shared__ float Zred[8 * 256];           // 8 KB  [wave][lane][reg]

    const int t    = threadIdx.x;
    const int w    = t >> 6;        // wave 0..7
    const int lane = t & 63;

    // phase-A role: half = node half (16 nodes), ksp = K-split slot (stride 128)
    const int m16  = lane & 15;     // D col (node); A row = m16&7
    const int quad = lane >> 4;     // 0..3
    const int half = w >> 2;        // 0..1
    const int ksp  = w & 3;         // 0..3
    const int arow = (m16 & 7) << 11;
    const int arot = (m16 & 7) << 3;

    // chain role: wave w owns local row w; lanes 32-63 mirror lanes 0-31
    const int ii   = lane & 31;     // node within block
    const long row = (long)blockIdx.x * RPW + w;
    const int rot  = w << 3;

    // ---- stage x row w into LDS as bf16 (swizzled): 64 lanes x 8 floats ----
    {
        const float* xr = x + row * NIN + lane * 8;
        float4 v0 = *(const float4*)xr;
        float4 v1 = *(const float4*)(xr + 4);
        uint4 pk;
        pk.x = pack2(v0.x, v0.y); pk.y = pack2(v0.z, v0.w);
        pk.z = pack2(v1.x, v1.y); pk.w = pack2(v1.z, v1.w);
        *(uint4*)&O[(w << 11) + ((lane * 8 + rot) & 2047)] = pk;
    }
    __syncthreads();

    // ---- prologue: main(0) over columns [0, 480), chunks ksp+4t ----
    floatx4 acc = {0.f, 0.f, 0.f, 0.f};
    {
        const ushort* wb = Wb + (size_t)(half * 16 + m16) * NCOLS;
        for (int kk = ksp * 32; kk < NIN - 32; kk += 128) {
            short8 a = *(const short8*)&O[arow + ((kk + quad * 8 + arot) & 2047)];
            short8 b = *(const short8*)&wb[kk + quad * 8];
            acc = __builtin_amdgcn_mfma_f32_16x16x32_bf16(a, b, acc, 0, 0, 0);
        }
    }

    for (int k = 0; k < NBLK; ++k) {
        const int i0 = k << 5;
        const int L0 = NIN + i0;
        const int g  = i0 + ii;     // this lane's eval-node index (mirrored)

        __syncthreads();            // barrier A: chain(k-1) O-writes visible

        // prefetch fp32 diag weights + bias (L2-hot; consumed in the chain)
        float wdg[32];
        {
            const float* wd = W + (size_t)g * NCOLS + L0;
            #pragma unroll
            for (int q = 0; q < 8; ++q)
                *(float4*)&wdg[q * 4] = *(const float4*)&wd[q * 4];
        }
        float bi = bias[g];

        // tail: K=32 MFMA over [L0-32, L0) — chunk 15+k, owner ksp=(15+k)&3
        if (ksp == ((k + 3) & 3)) {
            const ushort* wb = Wb + (size_t)(i0 + half * 16 + m16) * NCOLS;
            const int ts = L0 - 32;
            short8 a = *(const short8*)&O[arow + ((ts + quad * 8 + arot) & 2047)];
            short8 b = *(const short8*)&wb[ts + quad * 8];
            acc = __builtin_amdgcn_mfma_f32_16x16x32_bf16(a, b, acc, 0, 0, 0);
        }

        // D frag: lane q*16+n holds Z[m=4q+reg][n] — store contiguous per lane
        *(floatx4*)&Zred[(w << 8) + (lane << 2)] = acc;
        __syncthreads();            // barrier B

        // gather z for (row w, node ii): sum 4 K-split partials
        const int h = ii >> 4, n = ii & 15;
        const int ridx = ((w >> 2) << 6) + (n << 2) + (w & 3);
        float zacc = bi;
        #pragma unroll
        for (int p = 0; p < 4; ++p)
            zacc += Zred[(((h << 2) + p) << 8) + ridx];

        // issue main(k+1) over [0, L0): cols finalized before chain(k)
        floatx4 accN = {0.f, 0.f, 0.f, 0.f};
        if (k + 1 < NBLK) {
            const ushort* wb = Wb + (size_t)(i0 + 32 + half * 16 + m16) * NCOLS;
            #pragma unroll 4
            for (int kk = ksp * 32; kk < L0; kk += 128) {
                short8 a = *(const short8*)&O[arow + ((kk + quad * 8 + arot) & 2047)];
                short8 b = *(const short8*)&wb[kk + quad * 8];
                accN = __builtin_amdgcn_mfma_f32_16x16x32_bf16(a, b, accN, 0, 0, 0);
            }
        }

        // chain: 32 sequential sigmoid steps. readlane = SALU broadcast;
        // wdg[jj] == 0 for jj >= ii (W strictly lower-triangular) -> no branch.
        #pragma unroll
        for (int jj = 0; jj < 32; ++jj) {
            float zj = __builtin_bit_cast(float,
                __builtin_amdgcn_readlane(__builtin_bit_cast(int, zacc), jj));
            float oj = sigmoid5(zj);
            zacc = fmaf(wdg[jj], oj, zacc);
        }
        float o = sigmoid5(zacc);

        if (lane < 32) {
            O[(w << 11) + ((L0 + ii + rot) & 2047)] = f2bf(o);
            if (g >= OUT_BASE)
                out[row * NOUT + (g - OUT_BASE)] = o;
        }
        acc = accN;
    }
}

// ---------- launch ----------

extern "C" void kernel_launch(void* const* d_in, const int* in_sizes, int n_in,
                              void* d_out, int out_size, void* d_ws, size_t ws_size,
                              hipStream_t stream) {
    const float* x  = (const float*)d_in[0];   // [4096, 512]
    const float* W  = (const float*)d_in[1];   // [1536, 2048]
    const float* b  = (const float*)d_in[2];   // [1536]
    float* out = (float*)d_out;                // [4096, 256]
    ushort* Wb = (ushort*)d_ws;                // bf16 W copy (6.3 MB)

    int n8 = NEVAL * NCOLS / 8;                // 393216 x 16B stores
    wconv<<<n8 / 256, 256, 0, stream>>>(W, Wb, n8);
    ffnet<<<4096 / RPW, 512, 0, stream>>>(x, W, Wb, b, out);
}

// Round 6
// 451.862 us; speedup vs baseline: 1.0994x; 1.0994x over previous
//
#include <hip/hip_runtime.h>
#include <hip/hip_bf16.h>

#define NIN    512
#define NEVAL  1536
#define NCOLS  2048
#define NOUT   256
#define OUT_BASE 1280
#define NBLK   48       // NEVAL / 32

typedef __attribute__((ext_vector_type(8))) short short8;   // 8 bf16 (4 VGPRs)
typedef __attribute__((ext_vector_type(4))) float floatx4;  // MFMA C/D

// ---------- helpers ----------

__device__ __forceinline__ unsigned short f2bf(float f) {
    __hip_bfloat16 h = __float2bfloat16(f);
    return __builtin_bit_cast(unsigned short, h);
}
__device__ __forceinline__ unsigned pack2(float a, float b) {
    return (unsigned)f2bf(a) | ((unsigned)f2bf(b) << 16);
}
// sigmoid(clip(5z,-60,60)): clamp dropped — v_exp overflow gives exact 0/1.
__device__ __forceinline__ float sigmoid5(float z) {
    return __builtin_amdgcn_rcpf(1.0f + __expf(-5.0f * z));
}

// ---------- W fp32 -> bf16 (d_ws re-poisoned every launch, so rerun) ----------

__global__ __launch_bounds__(256) void wconv(const float* __restrict__ W,
                                             ushort* __restrict__ Wb, int n8) {
    int i = blockIdx.x * blockDim.x + threadIdx.x;
    if (i < n8) {
        float4 v0 = ((const float4*)W)[2 * i];
        float4 v1 = ((const float4*)W)[2 * i + 1];
        uint4 pk;
        pk.x = pack2(v0.x, v0.y); pk.y = pack2(v0.z, v0.w);
        pk.z = pack2(v1.x, v1.y); pk.w = pack2(v1.z, v1.w);
        ((uint4*)Wb)[i] = pk;
    }
}

// ---------- main kernel ----------
// 256 WGs x 1024 threads (16 waves). WG owns 16 batch rows; wave w owns row w.
// O[16][2048] bf16 in LDS, row r rotated by 8r elements (b128-aligned swizzle).
// Per 32-node block k (columns [L0, L0+32), L0 = 512+32k):
//   tail:  one K=32 MFMA over [L0-32, L0), gated to owning K-split slot
//   Zred:  16 waves' partials (2 node-halves x 8 K-splits) -> LDS -> gather
//   main:  MFMAs for block k+1 over [0, L0) issued before the chain
//   chain: 32 sequential steps, readlane broadcast (SALU broadcast)
// ROUND-6 FIX: diag weights held as 8 named float4 REGISTERS (wd0..wd7).
// The previous float wdg[32] was address-taken via *(float4*)& casts ->
// scratch-allocated (VGPR_Count was 40!) -> 32 serial scratch loads per
// block on the chain's critical path = the invariant ~395us across R2/4/5.

__global__ __launch_bounds__(1024) void ffnet(const float* __restrict__ x,
                                              const float* __restrict__ W,
                                              const ushort* __restrict__ Wb,
                                              const float* __restrict__ bias,
                                              float* __restrict__ out) {
    __shared__ unsigned short O[16 * 2048];   // 64 KB
    __shared__ float Zred[16 * 256];          // 16 KB  [wave][lane][reg]

    const int t    = threadIdx.x;
    const int w    = t >> 6;        // wave 0..15
    const int lane = t & 63;

    // phase-A role
    const int m16  = lane & 15;     // A row (batch row) / D col (node)
    const int quad = lane >> 4;     // 0..3
    const int half = w >> 3;        // 0..1
    const int ksp  = w & 7;         // 0..7
    const int arow = m16 << 11;
    const int arot = m16 << 3;

    // chain role: wave w owns local row w; lanes 32-63 mirror lanes 0-31
    const int ii   = lane & 31;
    const long row = (long)blockIdx.x * 16 + w;
    const int rot  = w << 3;

    // ---- stage x row w into LDS as bf16 (swizzled) ----
    {
        const float* xr = x + row * NIN + lane * 8;
        float4 v0 = *(const float4*)xr;
        float4 v1 = *(const float4*)(xr + 4);
        uint4 pk;
        pk.x = pack2(v0.x, v0.y); pk.y = pack2(v0.z, v0.w);
        pk.z = pack2(v1.x, v1.y); pk.w = pack2(v1.z, v1.w);
        *(uint4*)&O[(w << 11) + ((lane * 8 + rot) & 2047)] = pk;
    }
    __syncthreads();

    // ---- prologue: main(0) over columns [0, 480) ----
    floatx4 acc = {0.f, 0.f, 0.f, 0.f};
    {
        const ushort* wb = Wb + (size_t)(half * 16 + m16) * NCOLS;
        for (int kk = ksp * 32; kk < NIN - 32; kk += 256) {
            short8 a = *(const short8*)&O[arow + ((kk + quad * 8 + arot) & 2047)];
            short8 b = *(const short8*)&wb[kk + quad * 8];
            acc = __builtin_amdgcn_mfma_f32_16x16x32_bf16(a, b, acc, 0, 0, 0);
        }
    }

    for (int k = 0; k < NBLK; ++k) {
        const int i0 = k << 5;
        const int L0 = NIN + i0;
        const int g  = i0 + ii;     // this lane's eval-node index (mirrored)

        __syncthreads();            // barrier A: chain(k-1) O-writes visible

        // prefetch fp32 diag weights + bias into NAMED float4 regs (no
        // address-taken array -> stays in VGPRs)
        const float* wd = W + (size_t)g * NCOLS + L0;
        float4 wd0 = *(const float4*)(wd +  0);
        float4 wd1 = *(const float4*)(wd +  4);
        float4 wd2 = *(const float4*)(wd +  8);
        float4 wd3 = *(const float4*)(wd + 12);
        float4 wd4 = *(const float4*)(wd + 16);
        float4 wd5 = *(const float4*)(wd + 20);
        float4 wd6 = *(const float4*)(wd + 24);
        float4 wd7 = *(const float4*)(wd + 28);
        float bi = bias[g];

        // tail: K=32 MFMA over [L0-32, L0) — chunk 15+k, owner ksp=(k+7)&7
        if (ksp == ((k + 7) & 7)) {
            const ushort* wb = Wb + (size_t)(i0 + half * 16 + m16) * NCOLS;
            const int ts = L0 - 32;
            short8 a = *(const short8*)&O[arow + ((ts + quad * 8 + arot) & 2047)];
            short8 b = *(const short8*)&wb[ts + quad * 8];
            acc = __builtin_amdgcn_mfma_f32_16x16x32_bf16(a, b, acc, 0, 0, 0);
        }

        // D frag: lane q*16+n holds Z[m=4q+reg][n]
        *(floatx4*)&Zred[(w << 8) + (lane << 2)] = acc;
        __syncthreads();            // barrier B

        // gather z for (row w, node ii): sum 8 K-split partials
        const int h = ii >> 4, n = ii & 15;
        const int ridx = ((w >> 2) << 6) + (n << 2) + (w & 3);
        float zacc = bi;
        #pragma unroll
        for (int p = 0; p < 8; ++p)
            zacc += Zred[(((h << 3) + p) << 8) + ridx];

        // issue main(k+1) over [0, L0)
        floatx4 accN = {0.f, 0.f, 0.f, 0.f};
        if (k + 1 < NBLK) {
            const ushort* wb = Wb + (size_t)(i0 + 32 + half * 16 + m16) * NCOLS;
            #pragma unroll 2
            for (int kk = ksp * 32; kk < L0; kk += 256) {
                short8 a = *(const short8*)&O[arow + ((kk + quad * 8 + arot) & 2047)];
                short8 b = *(const short8*)&wb[kk + quad * 8];
                accN = __builtin_amdgcn_mfma_f32_16x16x32_bf16(a, b, accN, 0, 0, 0);
            }
        }

        // chain: 32 sequential sigmoid steps, fully unrolled with literal
        // lane index + register component (wd*.{xyzw} == 0 for jj >= ii).
        #define CH(JJ, WDC)                                                    \
            {                                                                  \
                float zj = __builtin_bit_cast(float,                           \
                    __builtin_amdgcn_readlane(                                 \
                        __builtin_bit_cast(int, zacc), JJ));                   \
                zacc = fmaf(WDC, sigmoid5(zj), zacc);                          \
            }
        CH( 0, wd0.x) CH( 1, wd0.y) CH( 2, wd0.z) CH( 3, wd0.w)
        CH( 4, wd1.x) CH( 5, wd1.y) CH( 6, wd1.z) CH( 7, wd1.w)
        CH( 8, wd2.x) CH( 9, wd2.y) CH(10, wd2.z) CH(11, wd2.w)
        CH(12, wd3.x) CH(13, wd3.y) CH(14, wd3.z) CH(15, wd3.w)
        CH(16, wd4.x) CH(17, wd4.y) CH(18, wd4.z) CH(19, wd4.w)
        CH(20, wd5.x) CH(21, wd5.y) CH(22, wd5.z) CH(23, wd5.w)
        CH(24, wd6.x) CH(25, wd6.y) CH(26, wd6.z) CH(27, wd6.w)
        CH(28, wd7.x) CH(29, wd7.y) CH(30, wd7.z) CH(31, wd7.w)
        #undef CH
        float o = sigmoid5(zacc);

        if (lane < 32) {
            O[(w << 11) + ((L0 + ii + rot) & 2047)] = f2bf(o);
            if (g >= OUT_BASE)
                out[row * NOUT + (g - OUT_BASE)] = o;
        }
        acc = accN;
    }
}

// ---------- launch ----------

extern "C" void kernel_launch(void* const* d_in, const int* in_sizes, int n_in,
                              void* d_out, int out_size, void* d_ws, size_t ws_size,
                              hipStream_t stream) {
    const float* x  = (const float*)d_in[0];   // [4096, 512]
    const float* W  = (const float*)d_in[1];   // [1536, 2048]
    const float* b  = (const float*)d_in[2];   // [1536]
    float* out = (float*)d_out;                // [4096, 256]
    ushort* Wb = (ushort*)d_ws;                // bf16 W copy (6.3 MB)

    int n8 = NEVAL * NCOLS / 8;
    wconv<<<n8 / 256, 256, 0, stream>>>(W, Wb, n8);
    ffnet<<<4096 / 16, 1024, 0, stream>>>(x, W, Wb, b, out);
}